// Round 3
// baseline (682.596 us; speedup 1.0000x reference)
//
#include <hip/hip_runtime.h>
#include <stdint.h>

#define HH 512
#define WW 512
#define NBATCH 16
#define IMG (HH*WW)          // 262144
#define NPIX (NBATCH*IMG)    // 4194304

// ---------- helpers ----------
__device__ __forceinline__ unsigned fkey(float f) {
    unsigned u = __float_as_uint(f);
    return (u & 0x80000000u) ? ~u : (u | 0x80000000u);
}
__device__ __forceinline__ float fdec(unsigned k) {
    unsigned u = (k & 0x80000000u) ? (k ^ 0x80000000u) : ~k;
    return __uint_as_float(u);
}
__device__ __forceinline__ int refl(int i) {   // reflect pad (no edge repeat), H=W=512, r<=4
    i = abs(i);
    return (i >= 512) ? (1022 - i) : i;
}
// CLAHE bilinear value (unscaled 0..255) — SINGLE definition used by K3 and K4 so the
// min/max reduced in K3 is bitwise-exact for the values K4 recomputes.
__device__ __forceinline__ float clahe_val(const float* __restrict__ lb /*luts + b*16384*/,
                                           int bin, int gy, int gx) {
    float py = ((float)gy + 0.5f) * 0.015625f - 0.5f;   // /64 exact
    float px = ((float)gx + 0.5f) * 0.015625f - 0.5f;
    int iy0 = (int)floorf(py);
    int ix0 = (int)floorf(px);
    float fy = py - (float)iy0;
    float fx = px - (float)ix0;
    int iy0c = max(iy0, 0), iy1c = min(iy0 + 1, 7);
    int ix0c = max(ix0, 0), ix1c = min(ix0 + 1, 7);
    const float* lr0 = lb + iy0c * (8 * 256);
    const float* lr1 = lb + iy1c * (8 * 256);
    float v00 = lr0[ix0c * 256 + bin], v01 = lr0[ix1c * 256 + bin];
    float v10 = lr1[ix0c * 256 + bin], v11 = lr1[ix1c * 256 + bin];
    return (1.0f - fy) * ((1.0f - fx) * v00 + fx * v01)
         + fy * ((1.0f - fx) * v10 + fx * v11);
}

// ---------- K0: init sentinels ----------
__global__ void k_init(unsigned* slots) {
    int t = threadIdx.x;
    if (t < 6) slots[t] = (t & 1) ? 0u : 0xFFFFFFFFu;  // even=min slot, odd=max slot
}

// ---------- K1: global min/max of x -> slots[0,1] ----------
__global__ __launch_bounds__(256) void k_minmax(const float4* __restrict__ x,
                                                unsigned* slots, int n4) {
    float m = 3.4e38f, M = -3.4e38f;
    for (int i = blockIdx.x * blockDim.x + threadIdx.x; i < n4; i += gridDim.x * blockDim.x) {
        float4 v = x[i];
        m = fminf(m, fminf(fminf(v.x, v.y), fminf(v.z, v.w)));
        M = fmaxf(M, fmaxf(fmaxf(v.x, v.y), fmaxf(v.z, v.w)));
    }
    for (int off = 32; off; off >>= 1) {
        m = fminf(m, __shfl_xor(m, off));
        M = fmaxf(M, __shfl_xor(M, off));
    }
    if ((threadIdx.x & 63) == 0) { atomicMin(slots + 0, fkey(m)); atomicMax(slots + 1, fkey(M)); }
}

// ---------- K2: normalize+log -> bins (u8); per-tile hist + LUT (one block / 64x64 tile) ----
// ~68% of pixels saturate to bin 255 (2.5*log2(1+x) clips at x~0.3195): hot bin counted in
// registers + wave-reduce, one LDS atomic per wave instead of per pixel.
__global__ __launch_bounds__(256) void k_hist_lut(const float* __restrict__ x,
                                                  const unsigned* __restrict__ slots,
                                                  unsigned char* __restrict__ bins,
                                                  float* __restrict__ luts) {
    __shared__ int hist[256];
    __shared__ float sc[256];
    int t = threadIdx.x;
    hist[t] = 0;
    int tl = blockIdx.x;            // 0..1023 = b*64 + gy*8 + gx
    int b = tl >> 6, ti = tl & 63;
    int row0 = (ti >> 3) * 64, col0 = (ti & 7) * 64;
    float mn = fdec(slots[0]), mx = fdec(slots[1]);
    float rng = mx - mn;
    __syncthreads();
    int tx = t & 63, ty = t >> 6;
    const float* xb = x + b * IMG;
    unsigned char* bb = bins + b * IMG;
    int cnt255 = 0;
    for (int r = 0; r < 16; ++r) {
        int row = row0 + ty + r * 4;
        int idx = row * WW + col0 + tx;
        float z = (xb[idx] - mn) / rng;                 // normalize01, exact div as reference
        float y = 2.5f * log2f(1.0f + z);               // precise log2: bin boundaries matter
        y = fminf(fmaxf(y, 0.0f), 1.0f);
        int bin = (int)(y * 256.0f);                    // *256 exact (pow2), trunc as reference
        bin = min(bin, 255);
        bb[idx] = (unsigned char)bin;
        if (bin == 255) cnt255++;
        else atomicAdd(&hist[bin], 1);
    }
    for (int off = 32; off; off >>= 1) cnt255 += __shfl_xor(cnt255, off);
    if ((t & 63) == 0) atomicAdd(&hist[255], cnt255);
    __syncthreads();
    // CLAHE LUT: clip@16, residual, inclusive scan. Bit-exact in ANY association: terms are
    // int<=16 plus k/256 dyadic; every partial sum needs <=21 mantissa bits.
    float cv = fminf((float)hist[t], 16.0f);
    sc[t] = cv;
    __syncthreads();
    for (int off = 1; off < 256; off <<= 1) {
        float add = (t >= off) ? sc[t - off] : 0.0f;
        __syncthreads();
        sc[t] += add;
        __syncthreads();
    }
    float total = sc[255];
    float residual = (4096.0f - total) * (1.0f / 256.0f);     // exact
    float cum = sc[t] + (float)(t + 1) * residual;            // exact
    float lutv = floorf(fminf(fmaxf(cum * (255.0f / 4096.0f), 0.0f), 255.0f));
    luts[tl * 256 + t] = lutv;
}

// ---------- K3: CLAHE apply, min/max ONLY (no store; K4 recomputes bit-identically) ------
__global__ __launch_bounds__(256) void k_clahe_minmax(const uchar4* __restrict__ bins,
                                                      const float* __restrict__ luts,
                                                      unsigned* slotsOut) {
    int i = blockIdx.x * blockDim.x + threadIdx.x;  // one uchar4 = 4 consecutive pixels
    int p = i << 2;
    int b = p >> 18;
    int rem = p & (IMG - 1);
    int h = rem >> 9;
    int w0 = rem & 511;
    const float* lb = luts + b * (64 * 256);
    uchar4 bn = bins[i];
    int ba[4] = {bn.x, bn.y, bn.z, bn.w};
    float m = 3.4e38f, M = -3.4e38f;
#pragma unroll
    for (int k = 0; k < 4; ++k) {
        float v = clahe_val(lb, ba[k], h, w0 + k);
        m = fminf(m, v); M = fmaxf(M, v);
    }
    for (int off = 32; off; off >>= 1) {
        m = fminf(m, __shfl_xor(m, off));
        M = fmaxf(M, __shfl_xor(M, off));
    }
    if ((threadIdx.x & 63) == 0) { atomicMin(slotsOut + 0, fkey(m)); atomicMax(slotsOut + 1, fkey(M)); }
}

// ---------- K4: recompute CLAHE -> normalize01 -> bilateral(5x5) -> gaussian(5x5) --------
// 64x64 output tile / 256-thread block. z (72x72) staged by recomputing CLAHE at reflected
// coords; bilateral over 68x68 into LDS. Halo bilateral values are evaluated at the
// REFLECTED source position so the gaussian sees reflect-padded bilateral output, matching
// the reference's pad-then-stack semantics.
#define TS 64
#define ZS 72
#define BS 68
__global__ __launch_bounds__(256) void k_bilat_gauss(const unsigned char* __restrict__ bins,
                                                     const float* __restrict__ luts,
                                                     const unsigned* __restrict__ slots,
                                                     float* __restrict__ outg,
                                                     unsigned* slotsOut) {
    __shared__ float z[ZS * ZS];    // 20.25 KB
    __shared__ float bb[BS * BS];   // 18.06 KB
    int t = threadIdx.x;
    int bid = blockIdx.x;           // 0..1023 = b*64 + tile
    int b = bid >> 6;
    int tid = bid & 63;
    int ty0 = (tid >> 3) * TS, tx0 = (tid & 7) * TS;
    float mn = fdec(slots[2]), mx = fdec(slots[3]);
    float inv = 1.0f / (mx - mn);
    const unsigned char* bimg = bins + b * IMG;
    const float* lb = luts + b * (64 * 256);
    // gaussian 1-D weights (sigma=1 for space and blur), same construction as reference
    float g0 = expf(-2.0f), g1 = expf(-0.5f);
    float gs = 1.0f + 2.0f * g0 + 2.0f * g1;
    float ga[5] = {g0 / gs, g1 / gs, 1.0f / gs, g1 / gs, g0 / gs};
    // stage z: recompute CLAHE at reflect(coord), normalize
    for (int j = t; j < ZS * ZS; j += 256) {
        int ly = j / ZS, lx = j - ly * ZS;
        int gy = refl(ty0 - 4 + ly);
        int gx = refl(tx0 - 4 + lx);
        float v = clahe_val(lb, (int)bimg[gy * WW + gx], gy, gx);
        z[j] = (v - mn) * inv;
    }
    __syncthreads();
    // bilateral over 68x68 (tile + 2 halo), halo at reflected source position
    for (int j = t; j < BS * BS; j += 256) {
        int ly = j / BS, lx = j - ly * BS;
        int gy = refl(ty0 - 2 + ly);
        int gx = refl(tx0 - 2 + lx);
        int zi = gy - ty0 + 4;   // 0..ZS-1, radius-2 neighborhood stays in bounds
        int zj = gx - tx0 + 4;
        float zc = z[zi * ZS + zj];
        float num = 0.0f, den = 0.0f;
#pragma unroll
        for (int dy = 0; dy < 5; ++dy)
#pragma unroll
            for (int dx = 0; dx < 5; ++dx) {
                float zn = z[(zi - 2 + dy) * ZS + (zj - 2 + dx)];
                float d = zn - zc;
                float wgt = __expf(-50.0f * d * d) * ga[dy] * ga[dx];  // smooth weight
                num += zn * wgt;
                den += wgt;
            }
        bb[j] = num / den;
    }
    __syncthreads();
    // gaussian 5x5, 16 outputs/thread; fused global min/max -> slots[4,5]
    float* ob = outg + b * IMG;
    float m = 3.4e38f, M = -3.4e38f;
    int ox = t & 63, oy0 = t >> 6;
#pragma unroll
    for (int r = 0; r < 16; ++r) {
        int oy = oy0 + r * 4;
        float s = 0.0f;
#pragma unroll
        for (int dy = 0; dy < 5; ++dy) {
            int bi = (oy + dy) * BS + ox;
#pragma unroll
            for (int dx = 0; dx < 5; ++dx)
                s += bb[bi + dx] * ga[dy] * ga[dx];
        }
        ob[(ty0 + oy) * WW + tx0 + ox] = s;
        m = fminf(m, s); M = fmaxf(M, s);
    }
    for (int off = 32; off; off >>= 1) {
        m = fminf(m, __shfl_xor(m, off));
        M = fmaxf(M, __shfl_xor(M, off));
    }
    if ((t & 63) == 0) { atomicMin(slotsOut + 0, fkey(m)); atomicMax(slotsOut + 1, fkey(M)); }
}

// ---------- K5: final normalize01 in-place on d_out ----------
__global__ __launch_bounds__(256) void k_final(float4* __restrict__ o,
                                               const unsigned* __restrict__ slots, int n4) {
    int i = blockIdx.x * blockDim.x + threadIdx.x;
    if (i >= n4) return;
    float mn = fdec(slots[4]), mx = fdec(slots[5]);
    float rng = mx - mn;
    float4 v = o[i];
    v.x = (v.x - mn) / rng;
    v.y = (v.y - mn) / rng;
    v.z = (v.z - mn) / rng;
    v.w = (v.w - mn) / rng;
    o[i] = v;
}

extern "C" void kernel_launch(void* const* d_in, const int* in_sizes, int n_in,
                              void* d_out, int out_size, void* d_ws, size_t ws_size,
                              hipStream_t stream) {
    const float* x = (const float*)d_in[0];
    float* out = (float*)d_out;
    char* ws = (char*)d_ws;
    // ws layout (~5.2 MB total): [0,1KB) slots | [1KB, +1MB) luts | [+1MB, +4MB) bins
    unsigned* slots = (unsigned*)ws;
    float* luts = (float*)(ws + 1024);
    unsigned char* bins = (unsigned char*)(ws + 1024 + (1 << 20));

    k_init<<<1, 64, 0, stream>>>(slots);
    k_minmax<<<1024, 256, 0, stream>>>((const float4*)x, slots, NPIX / 4);
    k_hist_lut<<<1024, 256, 0, stream>>>(x, slots, bins, luts);
    k_clahe_minmax<<<4096, 256, 0, stream>>>((const uchar4*)bins, luts, slots + 2);
    k_bilat_gauss<<<1024, 256, 0, stream>>>(bins, luts, slots, out, slots + 4);
    k_final<<<4096, 256, 0, stream>>>((float4*)out, slots, NPIX / 4);
}

// Round 6
// 398.862 us; speedup vs baseline: 1.7114x; 1.7114x over previous
//
#include <hip/hip_runtime.h>
#include <stdint.h>

#define HH 512
#define WW 512
#define NBATCH 16
#define IMG (HH*WW)          // 262144
#define NPIX (NBATCH*IMG)    // 4194304

// ---------- helpers ----------
__device__ __forceinline__ unsigned fkey(float f) {
    unsigned u = __float_as_uint(f);
    return (u & 0x80000000u) ? ~u : (u | 0x80000000u);
}
__device__ __forceinline__ float fdec(unsigned k) {
    unsigned u = (k & 0x80000000u) ? (k ^ 0x80000000u) : ~k;
    return __uint_as_float(u);
}
__device__ __forceinline__ int refl(int i) {   // reflect pad (no edge repeat), H=W=512, r<=4
    i = abs(i);
    return (i >= 512) ? (1022 - i) : i;
}
// Bilinear over the 3x3 LDS LUT block. slut layout: [corner 0..8][256 bins], corner = ly*3+lx
// (corner coords clamped at load time). IDENTICAL expression in K3 and K4 so K3's min/max
// matches K4's recomputed values.
__device__ __forceinline__ float bilerp_lds(const float* __restrict__ slut,
                                            int r0 /* (ly0*3+lx0)<<8 */, int bin,
                                            float fy, float fx) {
    float v00 = slut[r0 + bin];
    float v01 = slut[r0 + 256 + bin];
    float v10 = slut[r0 + 768 + bin];
    float v11 = slut[r0 + 1024 + bin];
    return (1.0f - fy) * ((1.0f - fx) * v00 + fx * v01)
         + fy * ((1.0f - fx) * v10 + fx * v11);
}

// ---------- K0: init sentinels ----------
__global__ void k_init(unsigned* slots) {
    int t = threadIdx.x;
    if (t < 6) slots[t] = (t & 1) ? 0u : 0xFFFFFFFFu;  // even=min slot, odd=max slot
}

// ---------- K1: global min/max of x -> slots[0,1] ----------
__global__ __launch_bounds__(256) void k_minmax(const float4* __restrict__ x,
                                                unsigned* slots, int n4) {
    float m = 3.4e38f, M = -3.4e38f;
    for (int i = blockIdx.x * blockDim.x + threadIdx.x; i < n4; i += gridDim.x * blockDim.x) {
        float4 v = x[i];
        m = fminf(m, fminf(fminf(v.x, v.y), fminf(v.z, v.w)));
        M = fmaxf(M, fmaxf(fmaxf(v.x, v.y), fmaxf(v.z, v.w)));
    }
    for (int off = 32; off; off >>= 1) {
        m = fminf(m, __shfl_xor(m, off));
        M = fmaxf(M, __shfl_xor(M, off));
    }
    if ((threadIdx.x & 63) == 0) { atomicMin(slots + 0, fkey(m)); atomicMax(slots + 1, fkey(M)); }
}

// ---------- K2: normalize+log -> bins (u8); per-tile hist + LUT (one block / 64x64 tile) ----
// ~68% of pixels saturate to bin 255: hot bin counted in registers + wave-reduce, one LDS
// atomic per wave instead of per pixel.
__global__ __launch_bounds__(256) void k_hist_lut(const float* __restrict__ x,
                                                  const unsigned* __restrict__ slots,
                                                  unsigned char* __restrict__ bins,
                                                  float* __restrict__ luts) {
    __shared__ int hist[256];
    __shared__ float sc[256];
    int t = threadIdx.x;
    hist[t] = 0;
    int tl = blockIdx.x;            // 0..1023 = b*64 + gy*8 + gx
    int b = tl >> 6, ti = tl & 63;
    int row0 = (ti >> 3) * 64, col0 = (ti & 7) * 64;
    float mn = fdec(slots[0]), mx = fdec(slots[1]);
    float rng = mx - mn;
    __syncthreads();
    int tx = t & 63, ty = t >> 6;
    const float* xb = x + b * IMG;
    unsigned char* bb = bins + b * IMG;
    int cnt255 = 0;
    for (int r = 0; r < 16; ++r) {
        int row = row0 + ty + r * 4;
        int idx = row * WW + col0 + tx;
        float z = (xb[idx] - mn) / rng;                 // normalize01, exact div as reference
        float y = 2.5f * log2f(1.0f + z);               // precise log2: bin boundaries matter
        y = fminf(fmaxf(y, 0.0f), 1.0f);
        int bin = (int)(y * 256.0f);                    // *256 exact (pow2), trunc as reference
        bin = min(bin, 255);
        bb[idx] = (unsigned char)bin;
        if (bin == 255) cnt255++;
        else atomicAdd(&hist[bin], 1);
    }
    for (int off = 32; off; off >>= 1) cnt255 += __shfl_xor(cnt255, off);
    if ((t & 63) == 0) atomicAdd(&hist[255], cnt255);
    __syncthreads();
    // CLAHE LUT: clip@16, residual, inclusive scan. Bit-exact in ANY association: terms are
    // int<=16 plus k/256 dyadic; every partial sum needs <=21 mantissa bits.
    float cv = fminf((float)hist[t], 16.0f);
    sc[t] = cv;
    __syncthreads();
    for (int off = 1; off < 256; off <<= 1) {
        float add = (t >= off) ? sc[t - off] : 0.0f;
        __syncthreads();
        sc[t] += add;
        __syncthreads();
    }
    float total = sc[255];
    float residual = (4096.0f - total) * (1.0f / 256.0f);     // exact
    float cum = sc[t] + (float)(t + 1) * residual;            // exact
    float lutv = floorf(fminf(fmaxf(cum * (255.0f / 4096.0f), 0.0f), 255.0f));
    luts[tl * 256 + t] = lutv;
}

// ---------- K3: CLAHE apply -> min/max only. One block per 64x64 tile; the 9 LUTs any
// pixel of this tile can touch (3x3 clamped neighborhood) staged in LDS; gathers hit LDS
// (broadcast-dominant: ~68% of bins == 255), not scattered global 4B loads. ----------
__global__ __launch_bounds__(256) void k_clahe_minmax(const unsigned char* __restrict__ bins,
                                                      const float* __restrict__ luts,
                                                      unsigned* slotsOut) {
    __shared__ float slut[9 * 256];   // 9 KB
    int t = threadIdx.x;
    int bid = blockIdx.x;             // 0..1023 = b*64 + tile
    int b = bid >> 6;
    int ti = bid & 63;
    int tgy = ti >> 3, tgx = ti & 7;
    const float* lb = luts + b * (64 * 256);
    for (int j = t; j < 9 * 256; j += 256) {
        int k = j >> 8;
        int cy = min(max(tgy - 1 + k / 3, 0), 7);
        int cx = min(max(tgx - 1 + k % 3, 0), 7);
        slut[j] = lb[(cy * 8 + cx) * 256 + (j & 255)];   // coalesced: 256 consecutive floats
    }
    __syncthreads();
    const unsigned char* bimg = bins + b * IMG;
    int lane = t & 63, wy = t >> 6;
    // per-lane column geometry (constant across rows)
    int gCol = tgx * 64 + lane;
    float px = ((float)gCol + 0.5f) * 0.015625f - 0.5f;
    int ix0 = (int)floorf(px);
    float fx = px - (float)ix0;
    int lx0 = ix0 - tgx + 1;          // 0 (lanes 0..31) or 1 (lanes 32..63)
    float m = 3.4e38f, M = -3.4e38f;
    for (int r = 0; r < 16; ++r) {
        int row = wy + r * 4;
        int gRow = tgy * 64 + row;
        float py = ((float)gRow + 0.5f) * 0.015625f - 0.5f;
        int iy0 = (int)floorf(py);
        float fy = py - (float)iy0;
        int ly0 = iy0 - tgy + 1;      // 0 or 1 (wave-uniform)
        int r0 = (ly0 * 3 + lx0) << 8;
        int bin = (int)bimg[gRow * WW + gCol];
        float v = bilerp_lds(slut, r0, bin, fy, fx);
        m = fminf(m, v); M = fmaxf(M, v);
    }
    for (int off = 32; off; off >>= 1) {
        m = fminf(m, __shfl_xor(m, off));
        M = fmaxf(M, __shfl_xor(M, off));
    }
    if ((t & 63) == 0) { atomicMin(slotsOut + 0, fkey(m)); atomicMax(slotsOut + 1, fkey(M)); }
}

// ---------- K4: recompute CLAHE (LDS LUTs) -> normalize01 -> bilateral(5x5) -> gaussian(5x5)
// 64x64 output tile / 256-thread block. z (72x72) staged by recomputing CLAHE at reflected
// coords; bilateral over 68x68 into LDS; halo bilateral values evaluated at the REFLECTED
// source position so the gaussian sees reflect-padded bilateral output (reference pad
// semantics). The 9-LUT block is unioned with bb (slut dead before bb is written).
#define TS 64
#define ZS 72
#define BS 68
__global__ __launch_bounds__(256) void k_bilat_gauss(const unsigned char* __restrict__ bins,
                                                     const float* __restrict__ luts,
                                                     const unsigned* __restrict__ slots,
                                                     float* __restrict__ outg,
                                                     unsigned* slotsOut) {
    __shared__ float z[ZS * ZS];      // 20.25 KB
    __shared__ float sb[BS * BS];     // 18.06 KB; [0,2304) doubles as slut during staging
    float* slut = sb;
    int t = threadIdx.x;
    int bid = blockIdx.x;             // 0..1023 = b*64 + tile
    int b = bid >> 6;
    int ti = bid & 63;
    int tgy = ti >> 3, tgx = ti & 7;
    int ty0 = tgy * TS, tx0 = tgx * TS;
    const float* lb = luts + b * (64 * 256);
    for (int j = t; j < 9 * 256; j += 256) {
        int k = j >> 8;
        int cy = min(max(tgy - 1 + k / 3, 0), 7);
        int cx = min(max(tgx - 1 + k % 3, 0), 7);
        slut[j] = lb[(cy * 8 + cx) * 256 + (j & 255)];
    }
    __syncthreads();
    float mn = fdec(slots[2]), mx = fdec(slots[3]);
    float inv = 1.0f / (mx - mn);
    const unsigned char* bimg = bins + b * IMG;
    // gaussian 1-D weights (sigma=1 for space and blur), same construction as reference
    float g0 = expf(-2.0f), g1 = expf(-0.5f);
    float gs = 1.0f + 2.0f * g0 + 2.0f * g1;
    float ga[5] = {g0 / gs, g1 / gs, 1.0f / gs, g1 / gs, g0 / gs};
    // stage z: recompute CLAHE from LDS LUTs at reflect(coord), normalize.
    // All tile+-4 pixels (after reflection) interpolate corners within the 3x3 block.
    for (int j = t; j < ZS * ZS; j += 256) {
        int ly = j / ZS, lx = j - ly * ZS;
        int gy = refl(ty0 - 4 + ly);
        int gx = refl(tx0 - 4 + lx);
        float py = ((float)gy + 0.5f) * 0.015625f - 0.5f;
        float px = ((float)gx + 0.5f) * 0.015625f - 0.5f;
        int iy0 = (int)floorf(py);
        int ix0 = (int)floorf(px);
        float fy = py - (float)iy0;
        float fx = px - (float)ix0;
        int r0 = ((iy0 - tgy + 1) * 3 + (ix0 - tgx + 1)) << 8;
        float v = bilerp_lds(slut, r0, (int)bimg[gy * WW + gx], fy, fx);
        z[j] = (v - mn) * inv;
    }
    __syncthreads();   // slut dead from here; sb becomes bb
    // bilateral over 68x68 (tile + 2 halo), halo at reflected source position.
    // Spatial weight factored per-row: num = sum_dy ga[dy]*(sum_dx zn*e*ga[dx]) — pure
    // reassociation of a positive-weighted sum (saves 2 VALU ops per tap).
    for (int j = t; j < BS * BS; j += 256) {
        int ly = j / BS, lx = j - ly * BS;
        int gy = refl(ty0 - 2 + ly);
        int gx = refl(tx0 - 2 + lx);
        int zi = gy - ty0 + 4;        // radius-2 neighborhood stays inside z
        int zj = gx - tx0 + 4;
        float zc = z[zi * ZS + zj];
        float num = 0.0f, den = 0.0f;
#pragma unroll
        for (int dy = 0; dy < 5; ++dy) {
            float rn = 0.0f, rd = 0.0f;
#pragma unroll
            for (int dx = 0; dx < 5; ++dx) {
                float zn = z[(zi - 2 + dy) * ZS + (zj - 2 + dx)];
                float d = zn - zc;
                float w = __expf(-50.0f * d * d) * ga[dx];   // smooth weight: fast exp ok
                rn += zn * w;
                rd += w;
            }
            num += ga[dy] * rn;
            den += ga[dy] * rd;
        }
        sb[j] = num / den;
    }
    __syncthreads();
    // gaussian 5x5, 16 outputs/thread; fused global min/max -> slots[4,5]
    float* ob = outg + b * IMG;
    float m = 3.4e38f, M = -3.4e38f;
    int ox = t & 63, oy0 = t >> 6;
#pragma unroll
    for (int r = 0; r < 16; ++r) {
        int oy = oy0 + r * 4;
        float s = 0.0f;
#pragma unroll
        for (int dy = 0; dy < 5; ++dy) {
            int bi = (oy + dy) * BS + ox;
            float rs = 0.0f;
#pragma unroll
            for (int dx = 0; dx < 5; ++dx)
                rs += sb[bi + dx] * ga[dx];
            s += rs * ga[dy];
        }
        ob[(ty0 + oy) * WW + tx0 + ox] = s;
        m = fminf(m, s); M = fmaxf(M, s);
    }
    for (int off = 32; off; off >>= 1) {
        m = fminf(m, __shfl_xor(m, off));
        M = fmaxf(M, __shfl_xor(M, off));
    }
    if ((t & 63) == 0) { atomicMin(slotsOut + 0, fkey(m)); atomicMax(slotsOut + 1, fkey(M)); }
}

// ---------- K5: final normalize01 in-place on d_out ----------
__global__ __launch_bounds__(256) void k_final(float4* __restrict__ o,
                                               const unsigned* __restrict__ slots, int n4) {
    int i = blockIdx.x * blockDim.x + threadIdx.x;
    if (i >= n4) return;
    float mn = fdec(slots[4]), mx = fdec(slots[5]);
    float rng = mx - mn;
    float4 v = o[i];
    v.x = (v.x - mn) / rng;
    v.y = (v.y - mn) / rng;
    v.z = (v.z - mn) / rng;
    v.w = (v.w - mn) / rng;
    o[i] = v;
}

extern "C" void kernel_launch(void* const* d_in, const int* in_sizes, int n_in,
                              void* d_out, int out_size, void* d_ws, size_t ws_size,
                              hipStream_t stream) {
    const float* x = (const float*)d_in[0];
    float* out = (float*)d_out;
    char* ws = (char*)d_ws;
    // ws layout (~5.2 MB total): [0,1KB) slots | [1KB, +1MB) luts | [+1MB, +4MB) bins
    unsigned* slots = (unsigned*)ws;
    float* luts = (float*)(ws + 1024);
    unsigned char* bins = (unsigned char*)(ws + 1024 + (1 << 20));

    k_init<<<1, 64, 0, stream>>>(slots);
    k_minmax<<<1024, 256, 0, stream>>>((const float4*)x, slots, NPIX / 4);
    k_hist_lut<<<1024, 256, 0, stream>>>(x, slots, bins, luts);
    k_clahe_minmax<<<1024, 256, 0, stream>>>(bins, luts, slots + 2);
    k_bilat_gauss<<<1024, 256, 0, stream>>>(bins, luts, slots, out, slots + 4);
    k_final<<<4096, 256, 0, stream>>>((float4*)out, slots, NPIX / 4);
}

// Round 12
// 386.823 us; speedup vs baseline: 1.7646x; 1.0311x over previous
//
#include <hip/hip_runtime.h>
#include <stdint.h>

#define HH 512
#define WW 512
#define NBATCH 16
#define IMG (HH*WW)          // 262144
#define NPIX (NBATCH*IMG)    // 4194304

// ---------- helpers ----------
__device__ __forceinline__ unsigned fkey(float f) {
    unsigned u = __float_as_uint(f);
    return (u & 0x80000000u) ? ~u : (u | 0x80000000u);
}
__device__ __forceinline__ float fdec(unsigned k) {
    unsigned u = (k & 0x80000000u) ? (k ^ 0x80000000u) : ~k;
    return __uint_as_float(u);
}
__device__ __forceinline__ int refl(int i) {   // reflect pad (no edge repeat), H=W=512, r<=4
    i = abs(i);
    return (i >= 512) ? (1022 - i) : i;
}
// Bilinear over the 3x3 LDS LUT block. slut layout: [corner 0..8][256 bins], corner = ly*3+lx
// (corner coords clamped at load time). IDENTICAL expression in K3 and K4 so K3's min/max
// matches K4's recomputed values.
__device__ __forceinline__ float bilerp_lds(const float* __restrict__ slut,
                                            int r0 /* (ly0*3+lx0)<<8 */, int bin,
                                            float fy, float fx) {
    float v00 = slut[r0 + bin];
    float v01 = slut[r0 + 256 + bin];
    float v10 = slut[r0 + 768 + bin];
    float v11 = slut[r0 + 1024 + bin];
    return (1.0f - fy) * ((1.0f - fx) * v00 + fx * v01)
         + fy * ((1.0f - fx) * v10 + fx * v11);
}

// ---------- K0: init sentinels ----------
__global__ void k_init(unsigned* slots) {
    int t = threadIdx.x;
    if (t < 6) slots[t] = (t & 1) ? 0u : 0xFFFFFFFFu;  // even=min slot, odd=max slot
}

// ---------- K1: global min/max of x -> slots[0,1] ----------
__global__ __launch_bounds__(256) void k_minmax(const float4* __restrict__ x,
                                                unsigned* slots, int n4) {
    float m = 3.4e38f, M = -3.4e38f;
    for (int i = blockIdx.x * blockDim.x + threadIdx.x; i < n4; i += gridDim.x * blockDim.x) {
        float4 v = x[i];
        m = fminf(m, fminf(fminf(v.x, v.y), fminf(v.z, v.w)));
        M = fmaxf(M, fmaxf(fmaxf(v.x, v.y), fmaxf(v.z, v.w)));
    }
    for (int off = 32; off; off >>= 1) {
        m = fminf(m, __shfl_xor(m, off));
        M = fmaxf(M, __shfl_xor(M, off));
    }
    if ((threadIdx.x & 63) == 0) { atomicMin(slots + 0, fkey(m)); atomicMax(slots + 1, fkey(M)); }
}

// ---------- K2: normalize+log -> bins (u8); per-tile hist + LUT (one block / 64x64 tile) ----
// float4 loads + uchar4 stores (4 px/thread/iter). ~68% of pixels saturate to bin 255:
// hot bin counted in registers + wave-reduce, one LDS atomic per wave.
__global__ __launch_bounds__(256) void k_hist_lut(const float* __restrict__ x,
                                                  const unsigned* __restrict__ slots,
                                                  unsigned char* __restrict__ bins,
                                                  float* __restrict__ luts) {
    __shared__ int hist[256];
    __shared__ float sc[256];
    int t = threadIdx.x;
    hist[t] = 0;
    int tl = blockIdx.x;            // 0..1023 = b*64 + gy*8 + gx
    int b = tl >> 6, ti = tl & 63;
    int row0 = (ti >> 3) * 64, col0 = (ti & 7) * 64;
    float mn = fdec(slots[0]), mx = fdec(slots[1]);
    float rng = mx - mn;
    __syncthreads();
    int lane = t & 63, wy = t >> 6;
    int sub = lane & 15, rq = lane >> 4;
    int cbase = col0 + sub * 4;
    const float* xb = x + b * IMG;
    unsigned char* bb = bins + b * IMG;
    int cnt255 = 0;
    for (int it = 0; it < 4; ++it) {
        int row = row0 + it * 16 + wy * 4 + rq;
        int idx = row * WW + cbase;
        float4 v4 = *(const float4*)(xb + idx);
        float vv[4] = {v4.x, v4.y, v4.z, v4.w};
        uchar4 b4;
        unsigned char bo[4];
#pragma unroll
        for (int k = 0; k < 4; ++k) {
            float z = (vv[k] - mn) / rng;               // normalize01, exact div as reference
            float y = 2.5f * log2f(1.0f + z);           // precise log2: bin boundaries matter
            y = fminf(fmaxf(y, 0.0f), 1.0f);
            int bin = (int)(y * 256.0f);
            bin = min(bin, 255);
            bo[k] = (unsigned char)bin;
            if (bin == 255) cnt255++;
            else atomicAdd(&hist[bin], 1);
        }
        b4.x = bo[0]; b4.y = bo[1]; b4.z = bo[2]; b4.w = bo[3];
        *(uchar4*)(bb + idx) = b4;
    }
    for (int off = 32; off; off >>= 1) cnt255 += __shfl_xor(cnt255, off);
    if ((t & 63) == 0) atomicAdd(&hist[255], cnt255);
    __syncthreads();
    // CLAHE LUT: clip@16, residual, inclusive scan. Bit-exact in ANY association: terms are
    // int<=16 plus k/256 dyadic; every partial sum needs <=21 mantissa bits.
    float cv = fminf((float)hist[t], 16.0f);
    sc[t] = cv;
    __syncthreads();
    for (int off = 1; off < 256; off <<= 1) {
        float add = (t >= off) ? sc[t - off] : 0.0f;
        __syncthreads();
        sc[t] += add;
        __syncthreads();
    }
    float total = sc[255];
    float residual = (4096.0f - total) * (1.0f / 256.0f);     // exact
    float cum = sc[t] + (float)(t + 1) * residual;            // exact
    float lutv = floorf(fminf(fmaxf(cum * (255.0f / 4096.0f), 0.0f), 255.0f));
    luts[tl * 256 + t] = lutv;
}

// ---------- K3: CLAHE apply -> min/max only. One block per 64x64 tile; 9 LUTs in LDS;
// uchar4 bin loads (4 px/thread/iter). ----------
__global__ __launch_bounds__(256) void k_clahe_minmax(const unsigned char* __restrict__ bins,
                                                      const float* __restrict__ luts,
                                                      unsigned* slotsOut) {
    __shared__ float slut[9 * 256];   // 9 KB
    int t = threadIdx.x;
    int bid = blockIdx.x;             // 0..1023 = b*64 + tile
    int b = bid >> 6;
    int ti = bid & 63;
    int tgy = ti >> 3, tgx = ti & 7;
    const float* lb = luts + b * (64 * 256);
    for (int j = t; j < 9 * 256; j += 256) {
        int k = j >> 8;
        int cy = min(max(tgy - 1 + k / 3, 0), 7);
        int cx = min(max(tgx - 1 + k % 3, 0), 7);
        slut[j] = lb[(cy * 8 + cx) * 256 + (j & 255)];   // coalesced: 256 consecutive floats
    }
    __syncthreads();
    const unsigned char* bimg = bins + b * IMG;
    int lane = t & 63, wy = t >> 6;
    int sub = lane & 15, rq = lane >> 4;
    int cb = sub * 4;                 // tile-local col of first of 4
    float fxk[4]; int lx0k[4];
#pragma unroll
    for (int k = 0; k < 4; ++k) {
        int gCol = tgx * 64 + cb + k;
        float px = ((float)gCol + 0.5f) * 0.015625f - 0.5f;
        int ix0 = (int)floorf(px);
        fxk[k] = px - (float)ix0;
        lx0k[k] = ix0 - tgx + 1;      // 0 or 1
    }
    float m = 3.4e38f, M = -3.4e38f;
    for (int it = 0; it < 4; ++it) {
        int row = it * 16 + wy * 4 + rq;
        int gRow = tgy * 64 + row;
        float py = ((float)gRow + 0.5f) * 0.015625f - 0.5f;
        int iy0 = (int)floorf(py);
        float fy = py - (float)iy0;
        int ly0 = iy0 - tgy + 1;      // 0 or 1 (wave-uniform)
        uchar4 b4 = *(const uchar4*)(bimg + gRow * WW + tgx * 64 + cb);
        int ba[4] = {b4.x, b4.y, b4.z, b4.w};
#pragma unroll
        for (int k = 0; k < 4; ++k) {
            int r0 = (ly0 * 3 + lx0k[k]) << 8;
            float v = bilerp_lds(slut, r0, ba[k], fy, fxk[k]);
            m = fminf(m, v); M = fmaxf(M, v);
        }
    }
    for (int off = 32; off; off >>= 1) {
        m = fminf(m, __shfl_xor(m, off));
        M = fmaxf(M, __shfl_xor(M, off));
    }
    if ((t & 63) == 0) { atomicMin(slotsOut + 0, fkey(m)); atomicMax(slotsOut + 1, fkey(M)); }
}

// ---------- K4: recompute CLAHE (LDS LUTs) -> normalize01 -> bilateral(5x5) -> separable
// gaussian(5). 64x64 tile / 256 threads. z 72x72 staged with reflect halo. Bilateral:
// interior 64x64 via 4-wide register-window strips (centers provably in-bounds, no refl);
// 528-pixel ring via per-pixel reflected-center path. Gaussian: h-pass (aliased onto dead z)
// then v-pass. slut unioned with sb. ----------
#define TS 64
#define ZS 72
#define BS 68
__global__ __launch_bounds__(256) void k_bilat_gauss(const unsigned char* __restrict__ bins,
                                                     const float* __restrict__ luts,
                                                     const unsigned* __restrict__ slots,
                                                     float* __restrict__ outg,
                                                     unsigned* slotsOut) {
    __shared__ float z[ZS * ZS];      // 20.25 KB; doubles as h-buffer [68][64] after bilateral
    __shared__ float sb[BS * BS];     // 18.06 KB; [0,2304) doubles as slut during staging
    float* slut = sb;
    int t = threadIdx.x;
    int bid = blockIdx.x;             // 0..1023 = b*64 + tile
    int b = bid >> 6;
    int ti = bid & 63;
    int tgy = ti >> 3, tgx = ti & 7;
    int ty0 = tgy * TS, tx0 = tgx * TS;
    const float* lb = luts + b * (64 * 256);
    for (int j = t; j < 9 * 256; j += 256) {
        int k = j >> 8;
        int cy = min(max(tgy - 1 + k / 3, 0), 7);
        int cx = min(max(tgx - 1 + k % 3, 0), 7);
        slut[j] = lb[(cy * 8 + cx) * 256 + (j & 255)];
    }
    __syncthreads();
    float mn = fdec(slots[2]), mx = fdec(slots[3]);
    float inv = 1.0f / (mx - mn);
    const unsigned char* bimg = bins + b * IMG;
    // gaussian 1-D weights (sigma=1 for space and blur), same construction as reference
    float g0 = expf(-2.0f), g1 = expf(-0.5f);
    float gs = 1.0f + 2.0f * g0 + 2.0f * g1;
    float ga[5] = {g0 / gs, g1 / gs, 1.0f / gs, g1 / gs, g0 / gs};
    // stage z: recompute CLAHE from LDS LUTs at reflect(coord), normalize
    for (int j = t; j < ZS * ZS; j += 256) {
        int ly = j / ZS, lx = j - ly * ZS;
        int gy = refl(ty0 - 4 + ly);
        int gx = refl(tx0 - 4 + lx);
        float py = ((float)gy + 0.5f) * 0.015625f - 0.5f;
        float px = ((float)gx + 0.5f) * 0.015625f - 0.5f;
        int iy0 = (int)floorf(py);
        int ix0 = (int)floorf(px);
        float fy = py - (float)iy0;
        float fx = px - (float)ix0;
        int r0 = ((iy0 - tgy + 1) * 3 + (ix0 - tgx + 1)) << 8;
        float v = bilerp_lds(slut, r0, (int)bimg[gy * WW + gx], fy, fx);
        z[j] = (v - mn) * inv;
    }
    __syncthreads();   // slut dead from here; sb becomes the bilateral buffer
    // ---- bilateral phase A: interior 64x64 (bb rows/cols 2..65), 4-wide register window.
    // bb(row,col) taps z[row+dy][col+dx]; strip (row_t, col0) loads z rows row_t+2..+6,
    // cols col0..col0+7 once into registers (all indices compile-time in unrolled loops).
    for (int it = 0; it < 4; ++it) {
        int task = t + it * 256;               // 0..1023
        int row_t = task >> 4;                 // 0..63
        int col0 = 2 + ((task & 15) << 2);     // 2,6,...,62
        float w[5][8];
#pragma unroll
        for (int dy = 0; dy < 5; ++dy)
#pragma unroll
            for (int k = 0; k < 8; ++k)
                w[dy][k] = z[(row_t + 2 + dy) * ZS + (col0 + k)];
        int sbase = (2 + row_t) * BS + col0;
#pragma unroll
        for (int i = 0; i < 4; ++i) {
            float zc = w[2][i + 2];
            float num = 0.0f, den = 0.0f;
#pragma unroll
            for (int dy = 0; dy < 5; ++dy) {
                float rn = 0.0f, rd = 0.0f;
#pragma unroll
                for (int dx = 0; dx < 5; ++dx) {
                    float zn = w[dy][i + dx];
                    float d = zn - zc;
                    float wt = __expf(-50.0f * d * d) * ga[dx];
                    rn += zn * wt;
                    rd += wt;
                }
                num += ga[dy] * rn;
                den += ga[dy] * rd;
            }
            sb[sbase + i] = num / den;
        }
    }
    // ---- bilateral phase B: 528-pixel ring, per-pixel reflected-center path
    for (int j = t; j < 528; j += 256) {
        int row, col;
        if (j < 136)      { row = j / 68;               col = j % 68; }
        else if (j < 272) { int jj = j - 136; row = 66 + jj / 68; col = jj % 68; }
        else              { int s = j - 272; row = 2 + (s >> 2);
                            int c2 = s & 3; col = (c2 & 1) + ((c2 & 2) ? 66 : 0); }
        int gy = refl(ty0 - 2 + row);
        int gx = refl(tx0 - 2 + col);
        int zi = gy - ty0 + 4;
        int zj = gx - tx0 + 4;
        float zc = z[zi * ZS + zj];
        float num = 0.0f, den = 0.0f;
#pragma unroll
        for (int dy = 0; dy < 5; ++dy) {
            float rn = 0.0f, rd = 0.0f;
#pragma unroll
            for (int dx = 0; dx < 5; ++dx) {
                float zn = z[(zi - 2 + dy) * ZS + (zj - 2 + dx)];
                float d = zn - zc;
                float wt = __expf(-50.0f * d * d) * ga[dx];
                rn += zn * wt;
                rd += wt;
            }
            num += ga[dy] * rn;
            den += ga[dy] * rd;
        }
        sb[row * BS + col] = num / den;
    }
    __syncthreads();
    // ---- gaussian h-pass: h[r][c] (r 0..67, c 0..63) into z-alias (z dead)
    float* hb = z;
    for (int j = t; j < 68 * 64; j += 256) {
        int r = j >> 6, c = j & 63;
        const float* srow = &sb[r * BS + c];
        float s = 0.0f;
#pragma unroll
        for (int dx = 0; dx < 5; ++dx) s += srow[dx] * ga[dx];
        hb[j] = s;
    }
    __syncthreads();
    // ---- gaussian v-pass: 16 outputs/thread; fused global min/max -> slots[4,5]
    float* ob = outg + b * IMG;
    float m = 3.4e38f, M = -3.4e38f;
    int ox = t & 63, oy0 = t >> 6;
#pragma unroll
    for (int r = 0; r < 16; ++r) {
        int oy = oy0 + r * 4;
        float s = 0.0f;
#pragma unroll
        for (int dy = 0; dy < 5; ++dy)
            s += hb[(oy + dy) * 64 + ox] * ga[dy];
        ob[(ty0 + oy) * WW + tx0 + ox] = s;
        m = fminf(m, s); M = fmaxf(M, s);
    }
    for (int off = 32; off; off >>= 1) {
        m = fminf(m, __shfl_xor(m, off));
        M = fmaxf(M, __shfl_xor(M, off));
    }
    if ((t & 63) == 0) { atomicMin(slotsOut + 0, fkey(m)); atomicMax(slotsOut + 1, fkey(M)); }
}

// ---------- K5: final normalize01 in-place on d_out ----------
__global__ __launch_bounds__(256) void k_final(float4* __restrict__ o,
                                               const unsigned* __restrict__ slots, int n4) {
    int i = blockIdx.x * blockDim.x + threadIdx.x;
    if (i >= n4) return;
    float mn = fdec(slots[4]), mx = fdec(slots[5]);
    float rng = mx - mn;
    float4 v = o[i];
    v.x = (v.x - mn) / rng;
    v.y = (v.y - mn) / rng;
    v.z = (v.z - mn) / rng;
    v.w = (v.w - mn) / rng;
    o[i] = v;
}

extern "C" void kernel_launch(void* const* d_in, const int* in_sizes, int n_in,
                              void* d_out, int out_size, void* d_ws, size_t ws_size,
                              hipStream_t stream) {
    const float* x = (const float*)d_in[0];
    float* out = (float*)d_out;
    char* ws = (char*)d_ws;
    // ws layout (~5.2 MB total): [0,1KB) slots | [1KB, +1MB) luts | [+1MB, +4MB) bins
    unsigned* slots = (unsigned*)ws;
    float* luts = (float*)(ws + 1024);
    unsigned char* bins = (unsigned char*)(ws + 1024 + (1 << 20));

    k_init<<<1, 64, 0, stream>>>(slots);
    k_minmax<<<1024, 256, 0, stream>>>((const float4*)x, slots, NPIX / 4);
    k_hist_lut<<<1024, 256, 0, stream>>>(x, slots, bins, luts);
    k_clahe_minmax<<<1024, 256, 0, stream>>>(bins, luts, slots + 2);
    k_bilat_gauss<<<1024, 256, 0, stream>>>(bins, luts, slots, out, slots + 4);
    k_final<<<4096, 256, 0, stream>>>((float4*)out, slots, NPIX / 4);
}